// Round 6
// baseline (1311.423 us; speedup 1.0000x reference)
//
#include <hip/hip_runtime.h>
#include <math.h>

#define NF 500
#define KPAD 512
#define NH 256
#define NC 40
#define P0 32        // plane-0 features (one 128B line)
#define P1 8         // plane-1 features (L2-resident plane)
#define KIT 10
#define LAMW 0.5f

typedef __attribute__((ext_vector_type(8))) short short8;
typedef __attribute__((ext_vector_type(4))) float f32x4;

__device__ __forceinline__ unsigned short bf_rne(float v) {
    unsigned int b = __float_as_uint(v);
    unsigned int h = (b + 0x7FFFu + ((b >> 16) & 1u)) >> 16;
    return (unsigned short)h;
}

// ---------------- weight prepass: transpose + bf16 hi/lo split ----------------
__global__ void w1prep_kernel(const float* __restrict__ W1, unsigned short* __restrict__ H,
                              unsigned short* __restrict__ L) {
    int k = blockIdx.x;        // 0..511
    int c = threadIdx.x;       // 0..255
    float v = (k < NF) ? W1[(size_t)k * NH + c] : 0.f;
    unsigned short h = bf_rne(v);
    float hf = __uint_as_float(((unsigned int)h) << 16);
    unsigned short lo = bf_rne(v - hf);
    H[(size_t)c * KPAD + k] = h;
    L[(size_t)c * KPAD + k] = lo;
}
__global__ void w2prep_kernel(const float* __restrict__ W2, unsigned short* __restrict__ H,
                              unsigned short* __restrict__ L) {
    int c = blockIdx.x;        // 0..47
    int k = threadIdx.x;       // 0..255
    float v = (c < NC) ? W2[(size_t)k * NC + c] : 0.f;
    unsigned short h = bf_rne(v);
    float hf = __uint_as_float(((unsigned int)h) << 16);
    unsigned short lo = bf_rne(v - hf);
    H[(size_t)c * NH + k] = h;
    L[(size_t)c * NH + k] = lo;
}

// ---------------- fused MLP via split-bf16 MFMA ----------------
__device__ __forceinline__ void mlp_load_tile(const float* __restrict__ xrow, int gr, int N,
                                              int skof, int tt, float v[8]) {
    if (gr < N && tt < 15) {
        float4 a = *(const float4*)(xrow + tt * 32);
        float4 b = *(const float4*)(xrow + tt * 32 + 4);
        v[0]=a.x; v[1]=a.y; v[2]=a.z; v[3]=a.w; v[4]=b.x; v[5]=b.y; v[6]=b.z; v[7]=b.w;
    } else {
        #pragma unroll
        for (int j = 0; j < 8; j++) {
            int k = tt * 32 + skof + j;
            v[j] = (gr < N && k < NF) ? xrow[tt * 32 + j] : 0.f;
        }
    }
}

// block = 256 thr (4 waves), 64 rows/block. Double-buffered A (20KB),
// GEMM2 in two k-halves (H half tile 34.8KB) -> 4 blocks/CU.
__global__ __launch_bounds__(256, 4) void mlp_mfma_kernel(
    const float* __restrict__ x, const float* __restrict__ b1,
    const unsigned short* __restrict__ W1tH, const unsigned short* __restrict__ W1tL,
    const unsigned short* __restrict__ W2tH, const unsigned short* __restrict__ W2tL,
    const float* __restrict__ b2, float* __restrict__ hp0, float* __restrict__ hp1, int N)
{
    __shared__ unsigned short smem[17408];     // 34.8 KB
    // phase1: A dbuf: buf b at b*5120 (hi), +2560 (lo), [64][40] each
    // phase2 (per half): Hhi = smem[0..8704), Hlo = smem[8704..17408), [64][136]
    unsigned short* Hhi = smem;
    unsigned short* Hlo = smem + 64 * 136;

    const int t   = threadIdx.x;
    const int w   = t >> 6;
    const int l   = t & 63;
    const int l15 = l & 15;
    const int lq  = l >> 4;
    const int row0 = blockIdx.x * 64;

    f32x4 acc[4][4];
    #pragma unroll
    for (int r = 0; r < 4; r++)
        #pragma unroll
        for (int c = 0; c < 4; c++) acc[r][c] = (f32x4){0.f, 0.f, 0.f, 0.f};

    const int srow = t >> 2;          // staging row 0..63
    const int skof = (t & 3) * 8;     // staging k-offset 0/8/16/24
    const int gr = row0 + srow;
    const float* xrow = x + (size_t)gr * NF + skof;

    float v_cur[8], v_nxt[8], v_p[8];
    mlp_load_tile(xrow, gr, N, skof, 0, v_cur);
    mlp_load_tile(xrow, gr, N, skof, 1, v_nxt);

    {   // convert+store tile0 -> buf0
        short8 sh, sl;
        #pragma unroll
        for (int j = 0; j < 8; j++) {
            unsigned int b = __float_as_uint(v_cur[j]);
            unsigned int h = (b + 0x7FFFu + ((b >> 16) & 1u)) >> 16;
            float hf = __uint_as_float(h << 16);
            float rr = v_cur[j] - hf;
            unsigned int rb = __float_as_uint(rr);
            unsigned int lo = (rb + 0x7FFFu + ((rb >> 16) & 1u)) >> 16;
            sh[j] = (short)h; sl[j] = (short)lo;
        }
        *(short8*)&smem[srow * 40 + skof] = sh;
        *(short8*)&smem[2560 + srow * 40 + skof] = sl;
    }
    __syncthreads();

    const size_t bB = (size_t)(64 * w + l15) * KPAD + lq * 8;   // W1t lane base
    for (int kt = 0; kt < 16; ++kt) {
        const int cur = kt & 1;
        short8 ah[4], al[4], bh[4], bl[4];
        #pragma unroll
        for (int r = 0; r < 4; r++) {
            ah[r] = *(short8*)&smem[cur * 5120 + (16 * r + l15) * 40 + lq * 8];
            al[r] = *(short8*)&smem[cur * 5120 + 2560 + (16 * r + l15) * 40 + lq * 8];
        }
        #pragma unroll
        for (int c = 0; c < 4; c++) {
            bh[c] = *(const short8*)&W1tH[bB + (size_t)c * 16 * KPAD + kt * 32];
            bl[c] = *(const short8*)&W1tL[bB + (size_t)c * 16 * KPAD + kt * 32];
        }
        if (kt < 14) mlp_load_tile(xrow, gr, N, skof, kt + 2, v_p);
        if (kt < 15) {
            short8 sh, sl;
            #pragma unroll
            for (int j = 0; j < 8; j++) {
                unsigned int b = __float_as_uint(v_nxt[j]);
                unsigned int h = (b + 0x7FFFu + ((b >> 16) & 1u)) >> 16;
                float hf = __uint_as_float(h << 16);
                float rr = v_nxt[j] - hf;
                unsigned int rb = __float_as_uint(rr);
                unsigned int lo = (rb + 0x7FFFu + ((rb >> 16) & 1u)) >> 16;
                sh[j] = (short)h; sl[j] = (short)lo;
            }
            *(short8*)&smem[(cur ^ 1) * 5120 + srow * 40 + skof] = sh;
            *(short8*)&smem[(cur ^ 1) * 5120 + 2560 + srow * 40 + skof] = sl;
        }
        #pragma unroll
        for (int c = 0; c < 4; c++)
            #pragma unroll
            for (int r = 0; r < 4; r++) {
                acc[r][c] = __builtin_amdgcn_mfma_f32_16x16x32_bf16(ah[r], bh[c], acc[r][c], 0, 0, 0);
                acc[r][c] = __builtin_amdgcn_mfma_f32_16x16x32_bf16(al[r], bh[c], acc[r][c], 0, 0, 0);
                acc[r][c] = __builtin_amdgcn_mfma_f32_16x16x32_bf16(ah[r], bl[c], acc[r][c], 0, 0, 0);
            }
        __syncthreads();
        if (kt < 14) {
            #pragma unroll
            for (int j = 0; j < 8; j++) v_nxt[j] = v_p[j];
        }
    }

    // GEMM2 in two k-halves: stage H[64 nodes][128 hid] (hi/lo), accumulate out^T
    f32x4 acc2[3];
    #pragma unroll
    for (int cf = 0; cf < 3; cf++) acc2[cf] = (f32x4){0.f, 0.f, 0.f, 0.f};

    #pragma unroll
    for (int hf2 = 0; hf2 < 2; ++hf2) {
        if ((w >> 1) == hf2) {
            // this wave's cols are in this half; local col = 64*(w&1)+16c+l15
            #pragma unroll
            for (int c = 0; c < 4; c++) {
                int lcol = 64 * (w & 1) + 16 * c + l15;
                float bb = b1[64 * w + 16 * c + l15];
                #pragma unroll
                for (int r = 0; r < 4; r++) {
                    #pragma unroll
                    for (int g = 0; g < 4; g++) {
                        float hval = fmaxf(acc[r][c][g] + bb, 0.f);
                        unsigned int hb = __float_as_uint(hval);
                        unsigned int h = (hb + 0x7FFFu + ((hb >> 16) & 1u)) >> 16;
                        float hff = __uint_as_float(h << 16);
                        float rr = hval - hff;
                        unsigned int rb = __float_as_uint(rr);
                        unsigned int lo = (rb + 0x7FFFu + ((rb >> 16) & 1u)) >> 16;
                        int rowi = 16 * r + lq * 4 + g;
                        Hhi[rowi * 136 + lcol] = (unsigned short)h;
                        Hlo[rowi * 136 + lcol] = (unsigned short)lo;
                    }
                }
            }
        }
        __syncthreads();
        const int hbase = (16 * w + l15) * 136 + lq * 8;
        const int wbase = l15 * NH + 128 * hf2 + lq * 8;
        #pragma unroll
        for (int kt = 0; kt < 4; ++kt) {
            short8 bhf = *(short8*)&Hhi[hbase + kt * 32];
            short8 blf = *(short8*)&Hlo[hbase + kt * 32];
            #pragma unroll
            for (int cf = 0; cf < 3; cf++) {
                short8 awh = *(const short8*)&W2tH[wbase + cf * 16 * NH + kt * 32];
                short8 awl = *(const short8*)&W2tL[wbase + cf * 16 * NH + kt * 32];
                acc2[cf] = __builtin_amdgcn_mfma_f32_16x16x32_bf16(awh, bhf, acc2[cf], 0, 0, 0);
                acc2[cf] = __builtin_amdgcn_mfma_f32_16x16x32_bf16(awl, bhf, acc2[cf], 0, 0, 0);
                acc2[cf] = __builtin_amdgcn_mfma_f32_16x16x32_bf16(awh, blf, acc2[cf], 0, 0, 0);
            }
        }
        __syncthreads();   // protect H overwrite (half B) / phase end
    }

    int node = row0 + 16 * w + l15;
    if (node < N) {
        #pragma unroll
        for (int cf = 0; cf < 3; cf++) {
            #pragma unroll
            for (int g = 0; g < 4; g++) {
                int cls = 16 * cf + lq * 4 + g;
                if (cls < P0) hp0[(size_t)node * P0 + cls] = acc2[cf][g] + b2[cls];
                else if (cls < NC) hp1[(size_t)node * P1 + (cls - P0)] = acc2[cf][g] + b2[cls];
            }
        }
    }
}

// ---------------- setup ----------------
__global__ void zero_int_kernel(int* p, int N) {
    int i = blockIdx.x * 256 + threadIdx.x;
    if (i < N) p[i] = 0;
}
__global__ void cnt_edges_kernel(const int* __restrict__ dst, int* cnt, int E) {
    int e = blockIdx.x * 256 + threadIdx.x;
    if (e < E) atomicAdd(&cnt[dst[e]], 1);
}
__global__ void dinv_kernel(const int* __restrict__ cnt, float* dinv, int N) {
    int i = blockIdx.x * 256 + threadIdx.x;
    if (i < N) dinv[i] = rsqrtf((float)cnt[i] + 1.0f);
}
__global__ __launch_bounds__(1024) void scanA_kernel(
    const int* __restrict__ cnt, int* __restrict__ rowptr, int* __restrict__ bsum, int N)
{
    __shared__ int sd[1024];
    int t = threadIdx.x;
    int i = blockIdx.x * 1024 + t;
    sd[t] = (i < N) ? (cnt[i] + 1) : 0;        // +1: self-loop entry
    __syncthreads();
    for (int off = 1; off < 1024; off <<= 1) {
        int v = (t >= off) ? sd[t - off] : 0;
        __syncthreads();
        if (t >= off) sd[t] += v;
        __syncthreads();
    }
    if (i < N) rowptr[i + 1] = sd[t];
    if (t == 1023) bsum[blockIdx.x] = sd[1023];
}
__global__ void scanB_kernel(int* bsum, int nb) {
    __shared__ int sb[256];
    int t = threadIdx.x;
    sb[t] = (t < nb) ? bsum[t] : 0;
    __syncthreads();
    if (t == 0) { int run = 0; for (int i = 0; i < nb; i++) { int v = sb[i]; sb[i] = run; run += v; } }
    __syncthreads();
    if (t < nb) bsum[t] = sb[t];
}
__global__ __launch_bounds__(1024) void scanC_kernel(int* rowptr, const int* __restrict__ bpre, int N) {
    int i = blockIdx.x * 1024 + threadIdx.x;
    if (i < N) rowptr[i + 1] += bpre[blockIdx.x];
    if (i == 0) rowptr[0] = 0;
}
__global__ void self_fill_kernel(const int* __restrict__ rowptr, const float* __restrict__ dinv,
                                 int2* __restrict__ csre, int* __restrict__ cursor, int N) {
    int i = blockIdx.x * 256 + threadIdx.x;
    if (i < N) {
        int p = rowptr[i];
        float d = dinv[i];
        csre[p] = make_int2(i, __float_as_int(d * d));
        cursor[i] = p + 1;
    }
}
__global__ void fill_csr_kernel(const int* __restrict__ src, const int* __restrict__ dst,
    const float* __restrict__ dinv, int* cursor, int2* __restrict__ csre, int E)
{
    int e = blockIdx.x * 256 + threadIdx.x;
    if (e < E) {
        int d = dst[e], s = src[e];
        int p = atomicAdd(&cursor[d], 1);
        csre[p] = make_int2(s, __float_as_int(dinv[s] * dinv[d]));
    }
}

// ---------------- AMP iteration: wave/node, two-plane xk, 16 edges in flight ----------------
// lane l: edge slot g = l>>3 (0..7), feature slot j = l&7.
// plane0: features 4j..4j+3 (float4, one 128B line per edge row, L3)
// plane1: feature 32+j (scalar, 3.2MB plane -> L2-resident)
__global__ __launch_bounds__(256, 8) void amp4_kernel(
    const float* __restrict__ xp0, const float* __restrict__ xp1,
    const float* __restrict__ hp0, const float* __restrict__ hp1,
    const int* __restrict__ rowptr, const int2* __restrict__ csre,
    float* __restrict__ np0, float* __restrict__ np1,
    float* __restrict__ lsm_out, float* __restrict__ score_out, int N, int last)
{
    const int n = (blockIdx.x * 256 + threadIdx.x) >> 6;
    if (n >= N) return;
    const int l = threadIdx.x & 63;
    const int g = l >> 3;
    const int j = l & 7;

    const int e0 = rowptr[n];
    const int e1 = rowptr[n + 1];     // >= e0+1 (self-loop)
    const int em = e1 - 1;

    float ax = 0.f, ay = 0.f, az = 0.f, aw = 0.f, a5 = 0.f;
    for (int base = e0; base < e1; base += 16) {
        int ea = base + g;
        int eb = base + 8 + g;
        bool va = ea < e1;
        bool vb = eb < e1;
        int2 pa = csre[va ? ea : em];
        int2 pb = csre[vb ? eb : em];
        const float4 ra = *(const float4*)(xp0 + ((size_t)pa.x << 5) + (j << 2));
        const float4 rb = *(const float4*)(xp0 + ((size_t)pb.x << 5) + (j << 2));
        float sa = xp1[((size_t)pa.x << 3) + j];
        float sb = xp1[((size_t)pb.x << 3) + j];
        float wa = va ? __int_as_float(pa.y) : 0.f;
        float wb = vb ? __int_as_float(pb.y) : 0.f;
        ax += wa * ra.x + wb * rb.x;
        ay += wa * ra.y + wb * rb.y;
        az += wa * ra.z + wb * rb.z;
        aw += wa * ra.w + wb * rb.w;
        a5 += wa * sa + wb * sb;
    }
    // reduce across 8 edge slots (bits 3,4,5)
    ax += __shfl_xor(ax, 8);  ay += __shfl_xor(ay, 8);
    az += __shfl_xor(az, 8);  aw += __shfl_xor(aw, 8);  a5 += __shfl_xor(a5, 8);
    ax += __shfl_xor(ax, 16); ay += __shfl_xor(ay, 16);
    az += __shfl_xor(az, 16); aw += __shfl_xor(aw, 16); a5 += __shfl_xor(a5, 16);
    ax += __shfl_xor(ax, 32); ay += __shfl_xor(ay, 32);
    az += __shfl_xor(az, 32); aw += __shfl_xor(aw, 32); a5 += __shfl_xor(a5, 32);

    const float4 h4 = *(const float4*)(hp0 + ((size_t)n << 5) + (j << 2));
    const float h5 = hp1[((size_t)n << 3) + j];
    float dx = ax - h4.x, dy = ay - h4.y, dz = az - h4.z, dw = aw - h4.w, d5 = a5 - h5;
    float d2 = dx * dx + dy * dy + dz * dz + dw * dw + d5 * d5;
    // reduce across 8 feature slots (bits 0,1,2)
    d2 += __shfl_xor(d2, 1); d2 += __shfl_xor(d2, 2); d2 += __shfl_xor(d2, 4);

    float rn = sqrtf(d2);
    float sc = (rn > LAMW) ? (rn - LAMW) / rn : 0.f;
    float4 xn;
    xn.x = h4.x + sc * dx; xn.y = h4.y + sc * dy;
    xn.z = h4.z + sc * dz; xn.w = h4.w + sc * dw;
    float x5 = h5 + sc * d5;

    if (!last) {
        if (g == 0) {
            *(float4*)(np0 + ((size_t)n << 5) + (j << 2)) = xn;
            np1[((size_t)n << 3) + j] = x5;
        }
    } else {
        if (l == 0) score_out[n] = sc;
        float m = fmaxf(fmaxf(fmaxf(xn.x, xn.y), fmaxf(xn.z, xn.w)), x5);
        m = fmaxf(m, __shfl_xor(m, 1));
        m = fmaxf(m, __shfl_xor(m, 2));
        m = fmaxf(m, __shfl_xor(m, 4));
        float es = expf(xn.x - m) + expf(xn.y - m) + expf(xn.z - m)
                 + expf(xn.w - m) + expf(x5 - m);
        es += __shfl_xor(es, 1); es += __shfl_xor(es, 2); es += __shfl_xor(es, 4);
        float lse = m + logf(es);
        if (g == 0) {
            float4 o;
            o.x = xn.x - lse; o.y = xn.y - lse; o.z = xn.z - lse; o.w = xn.w - lse;
            *(float4*)(lsm_out + (size_t)n * NC + (j << 2)) = o;
            lsm_out[(size_t)n * NC + P0 + j] = x5 - lse;
        }
    }
}

extern "C" void kernel_launch(void* const* d_in, const int* in_sizes, int n_in,
                              void* d_out, int out_size, void* d_ws, size_t ws_size,
                              hipStream_t stream)
{
    const float* x  = (const float*)d_in[0];
    const float* W1 = (const float*)d_in[1];
    const float* b1 = (const float*)d_in[2];
    const float* W2 = (const float*)d_in[3];
    const float* b2 = (const float*)d_in[4];
    const int* esrc = (const int*)d_in[5];
    const int* edst = (const int*)d_in[6];
    const int N = in_sizes[0] / NF;
    const int E = in_sizes[5];

    char* W = (char*)d_ws;
    size_t o = 0;
    float* hh0 = (float*)(W + o); o += (size_t)N * P0 * 4;
    float* hh1 = (float*)(W + o); o += (size_t)N * P1 * 4;
    float* a0  = (float*)(W + o); o += (size_t)N * P0 * 4;   // ping p0
    float* a1  = (float*)(W + o); o += (size_t)N * P1 * 4;   // ping p1
    float* c0  = (float*)(W + o); o += (size_t)N * P0 * 4;   // pong p0
    float* c1  = (float*)(W + o); o += (size_t)N * P1 * 4;   // pong p1
    float* dinv = (float*)(W + o); o += (size_t)N * 4;
    int* rowptr = (int*)(W + o);   o += (size_t)(N + 1) * 4;
    int* cnt    = (int*)(W + o);   o += (size_t)N * 4;
    int* bsum   = (int*)(W + o);   o += 256 * 4;
    o = (o + 15) & ~(size_t)15;
    int2* csre  = (int2*)(W + o);  o += (size_t)(E + N) * 8;   // edges + self-loops
    o = (o + 15) & ~(size_t)15;
    unsigned short* W1tH = (unsigned short*)(W + o); o += (size_t)NH * KPAD * 2;
    unsigned short* W1tL = (unsigned short*)(W + o); o += (size_t)NH * KPAD * 2;
    unsigned short* W2tH = (unsigned short*)(W + o); o += (size_t)48 * NH * 2;
    unsigned short* W2tL = (unsigned short*)(W + o); o += (size_t)48 * NH * 2;

    float* lsm = (float*)d_out;
    float* sco = lsm + (size_t)N * NC;

    const int gb = (N + 255) / 256;
    const int ge = (E + 255) / 256;
    const int nb = (N + 1023) / 1024;

    w1prep_kernel<<<KPAD, NH, 0, stream>>>(W1, W1tH, W1tL);
    w2prep_kernel<<<48, NH, 0, stream>>>(W2, W2tH, W2tL);
    mlp_mfma_kernel<<<(N + 63) / 64, 256, 0, stream>>>(x, b1, W1tH, W1tL, W2tH, W2tL, b2, hh0, hh1, N);

    zero_int_kernel<<<gb, 256, 0, stream>>>(cnt, N);
    cnt_edges_kernel<<<ge, 256, 0, stream>>>(edst, cnt, E);
    dinv_kernel<<<gb, 256, 0, stream>>>(cnt, dinv, N);
    scanA_kernel<<<nb, 1024, 0, stream>>>(cnt, rowptr, bsum, N);
    scanB_kernel<<<1, 256, 0, stream>>>(bsum, nb);
    scanC_kernel<<<nb, 1024, 0, stream>>>(rowptr, bsum, N);
    self_fill_kernel<<<gb, 256, 0, stream>>>(rowptr, dinv, csre, cnt, N);   // cnt reused as cursor
    fill_csr_kernel<<<ge, 256, 0, stream>>>(esrc, edst, dinv, cnt, csre, E);

    const float* xo0 = hh0;
    const float* xo1 = hh1;
    float* b0[2] = {a0, c0};
    float* b1p[2] = {a1, c1};
    for (int k = 0; k < KIT; k++) {
        int last = (k == KIT - 1);
        float* n0 = b0[k & 1];
        float* n1 = b1p[k & 1];
        amp4_kernel<<<(N + 3) / 4, 256, 0, stream>>>(
            xo0, xo1, hh0, hh1, rowptr, csre, n0, n1, lsm, sco, N, last);
        xo0 = n0; xo1 = n1;
    }
}

// Round 11
// 1050.088 us; speedup vs baseline: 1.2489x; 1.2489x over previous
//
#include <hip/hip_runtime.h>
#include <hip/hip_fp16.h>
#include <math.h>

#define NF 500
#define KPAD 512
#define NH 256
#define NC 40
#define KIT 10
#define LAMW 0.5f

typedef __attribute__((ext_vector_type(8))) short short8;
typedef __attribute__((ext_vector_type(4))) float f32x4;

__device__ __forceinline__ unsigned short bf_rne(float v) {
    unsigned int b = __float_as_uint(v);
    unsigned int h = (b + 0x7FFFu + ((b >> 16) & 1u)) >> 16;
    return (unsigned short)h;
}

// ---------------- weight prepass: transpose + bf16 hi/lo split ----------------
__global__ void w1prep_kernel(const float* __restrict__ W1, unsigned short* __restrict__ H,
                              unsigned short* __restrict__ L) {
    int k = blockIdx.x;        // 0..511
    int c = threadIdx.x;       // 0..255
    float v = (k < NF) ? W1[(size_t)k * NH + c] : 0.f;
    unsigned short h = bf_rne(v);
    float hf = __uint_as_float(((unsigned int)h) << 16);
    unsigned short lo = bf_rne(v - hf);
    H[(size_t)c * KPAD + k] = h;
    L[(size_t)c * KPAD + k] = lo;
}
__global__ void w2prep_kernel(const float* __restrict__ W2, unsigned short* __restrict__ H,
                              unsigned short* __restrict__ L) {
    int c = blockIdx.x;        // 0..47
    int k = threadIdx.x;       // 0..255
    float v = (c < NC) ? W2[(size_t)k * NC + c] : 0.f;
    unsigned short h = bf_rne(v);
    float hf = __uint_as_float(((unsigned int)h) << 16);
    unsigned short lo = bf_rne(v - hf);
    H[(size_t)c * NH + k] = h;
    L[(size_t)c * NH + k] = lo;
}

// ---------------- fused MLP via split-bf16 MFMA ----------------
__device__ __forceinline__ void mlp_load_tile(const float* __restrict__ xrow, int gr, int N,
                                              int skof, int tt, float v[8]) {
    if (gr < N && tt < 15) {
        float4 a = *(const float4*)(xrow + tt * 32);
        float4 b = *(const float4*)(xrow + tt * 32 + 4);
        v[0]=a.x; v[1]=a.y; v[2]=a.z; v[3]=a.w; v[4]=b.x; v[5]=b.y; v[6]=b.z; v[7]=b.w;
    } else {
        #pragma unroll
        for (int j = 0; j < 8; j++) {
            int k = tt * 32 + skof + j;
            v[j] = (gr < N && k < NF) ? xrow[tt * 32 + j] : 0.f;
        }
    }
}

// block = 256 thr (4 waves), 64 rows/block. A dbuf 20KB; GEMM2 two k-halves (34.8KB LDS).
// launch_bounds(256,2): do NOT cap VGPRs below need (R6: cap=64 spilled acc -> 549MB scratch).
__global__ __launch_bounds__(256, 2) void mlp_mfma_kernel(
    const float* __restrict__ x, const float* __restrict__ b1,
    const unsigned short* __restrict__ W1tH, const unsigned short* __restrict__ W1tL,
    const unsigned short* __restrict__ W2tH, const unsigned short* __restrict__ W2tL,
    const float* __restrict__ b2, float* __restrict__ hh, __half* __restrict__ xh0, int N)
{
    __shared__ unsigned short smem[17408];     // 34.8 KB
    unsigned short* Hhi = smem;                // phase2: [64][136] hi
    unsigned short* Hlo = smem + 64 * 136;     // phase2: [64][136] lo

    const int t   = threadIdx.x;
    const int w   = t >> 6;
    const int l   = t & 63;
    const int l15 = l & 15;
    const int lq  = l >> 4;
    const int row0 = blockIdx.x * 64;

    f32x4 acc[4][4];
    #pragma unroll
    for (int r = 0; r < 4; r++)
        #pragma unroll
        for (int c = 0; c < 4; c++) acc[r][c] = (f32x4){0.f, 0.f, 0.f, 0.f};

    const int srow = t >> 2;
    const int skof = (t & 3) * 8;
    const int gr = row0 + srow;
    const float* xrow = x + (size_t)gr * NF + skof;

    float v_cur[8], v_nxt[8], v_p[8];
    mlp_load_tile(xrow, gr, N, skof, 0, v_cur);
    mlp_load_tile(xrow, gr, N, skof, 1, v_nxt);

    {   // convert+store tile0 -> buf0
        short8 sh, sl;
        #pragma unroll
        for (int j = 0; j < 8; j++) {
            unsigned int b = __float_as_uint(v_cur[j]);
            unsigned int h = (b + 0x7FFFu + ((b >> 16) & 1u)) >> 16;
            float hf = __uint_as_float(h << 16);
            float rr = v_cur[j] - hf;
            unsigned int rb = __float_as_uint(rr);
            unsigned int lo = (rb + 0x7FFFu + ((rb >> 16) & 1u)) >> 16;
            sh[j] = (short)h; sl[j] = (short)lo;
        }
        *(short8*)&smem[srow * 40 + skof] = sh;
        *(short8*)&smem[2560 + srow * 40 + skof] = sl;
    }
    __syncthreads();

    const size_t bB = (size_t)(64 * w + l15) * KPAD + lq * 8;
    for (int kt = 0; kt < 16; ++kt) {
        const int cur = kt & 1;
        short8 ah[4], al[4], bh[4], bl[4];
        #pragma unroll
        for (int r = 0; r < 4; r++) {
            ah[r] = *(short8*)&smem[cur * 5120 + (16 * r + l15) * 40 + lq * 8];
            al[r] = *(short8*)&smem[cur * 5120 + 2560 + (16 * r + l15) * 40 + lq * 8];
        }
        #pragma unroll
        for (int c = 0; c < 4; c++) {
            bh[c] = *(const short8*)&W1tH[bB + (size_t)c * 16 * KPAD + kt * 32];
            bl[c] = *(const short8*)&W1tL[bB + (size_t)c * 16 * KPAD + kt * 32];
        }
        if (kt < 14) mlp_load_tile(xrow, gr, N, skof, kt + 2, v_p);
        if (kt < 15) {
            short8 sh, sl;
            #pragma unroll
            for (int j = 0; j < 8; j++) {
                unsigned int b = __float_as_uint(v_nxt[j]);
                unsigned int h = (b + 0x7FFFu + ((b >> 16) & 1u)) >> 16;
                float hf = __uint_as_float(h << 16);
                float rr = v_nxt[j] - hf;
                unsigned int rb = __float_as_uint(rr);
                unsigned int lo = (rb + 0x7FFFu + ((rb >> 16) & 1u)) >> 16;
                sh[j] = (short)h; sl[j] = (short)lo;
            }
            *(short8*)&smem[(cur ^ 1) * 5120 + srow * 40 + skof] = sh;
            *(short8*)&smem[(cur ^ 1) * 5120 + 2560 + srow * 40 + skof] = sl;
        }
        #pragma unroll
        for (int c = 0; c < 4; c++)
            #pragma unroll
            for (int r = 0; r < 4; r++) {
                acc[r][c] = __builtin_amdgcn_mfma_f32_16x16x32_bf16(ah[r], bh[c], acc[r][c], 0, 0, 0);
                acc[r][c] = __builtin_amdgcn_mfma_f32_16x16x32_bf16(al[r], bh[c], acc[r][c], 0, 0, 0);
                acc[r][c] = __builtin_amdgcn_mfma_f32_16x16x32_bf16(ah[r], bl[c], acc[r][c], 0, 0, 0);
            }
        __syncthreads();
        if (kt < 14) {
            #pragma unroll
            for (int j = 0; j < 8; j++) v_nxt[j] = v_p[j];
        }
    }

    // GEMM2 in two k-halves: stage H[64 nodes][128 hid] hi/lo, accumulate out^T
    f32x4 acc2[3];
    #pragma unroll
    for (int cf = 0; cf < 3; cf++) acc2[cf] = (f32x4){0.f, 0.f, 0.f, 0.f};

    #pragma unroll
    for (int hf2 = 0; hf2 < 2; ++hf2) {
        if ((w >> 1) == hf2) {
            #pragma unroll
            for (int c = 0; c < 4; c++) {
                int lcol = 64 * (w & 1) + 16 * c + l15;
                float bb = b1[64 * w + 16 * c + l15];
                #pragma unroll
                for (int r = 0; r < 4; r++) {
                    #pragma unroll
                    for (int g = 0; g < 4; g++) {
                        float hval = fmaxf(acc[r][c][g] + bb, 0.f);
                        unsigned int hb = __float_as_uint(hval);
                        unsigned int h = (hb + 0x7FFFu + ((hb >> 16) & 1u)) >> 16;
                        float hff = __uint_as_float(h << 16);
                        float rr = hval - hff;
                        unsigned int rb = __float_as_uint(rr);
                        unsigned int lo = (rb + 0x7FFFu + ((rb >> 16) & 1u)) >> 16;
                        int rowi = 16 * r + lq * 4 + g;
                        Hhi[rowi * 136 + lcol] = (unsigned short)h;
                        Hlo[rowi * 136 + lcol] = (unsigned short)lo;
                    }
                }
            }
        }
        __syncthreads();
        const int hbase = (16 * w + l15) * 136 + lq * 8;
        const int wbase = l15 * NH + 128 * hf2 + lq * 8;
        #pragma unroll
        for (int kt = 0; kt < 4; ++kt) {
            short8 bhf = *(short8*)&Hhi[hbase + kt * 32];
            short8 blf = *(short8*)&Hlo[hbase + kt * 32];
            #pragma unroll
            for (int cf = 0; cf < 3; cf++) {
                short8 awh = *(const short8*)&W2tH[wbase + cf * 16 * NH + kt * 32];
                short8 awl = *(const short8*)&W2tL[wbase + cf * 16 * NH + kt * 32];
                acc2[cf] = __builtin_amdgcn_mfma_f32_16x16x32_bf16(awh, bhf, acc2[cf], 0, 0, 0);
                acc2[cf] = __builtin_amdgcn_mfma_f32_16x16x32_bf16(awl, bhf, acc2[cf], 0, 0, 0);
                acc2[cf] = __builtin_amdgcn_mfma_f32_16x16x32_bf16(awh, blf, acc2[cf], 0, 0, 0);
            }
        }
        __syncthreads();
    }

    int node = row0 + 16 * w + l15;
    if (node < N) {
        size_t ob = (size_t)node << 6;       // padded [N][64]
        #pragma unroll
        for (int cf = 0; cf < 3; cf++) {
            #pragma unroll
            for (int g = 0; g < 4; g++) {
                int cls = 16 * cf + lq * 4 + g;
                float val = (cls < NC) ? (acc2[cf][g] + b2[cls]) : 0.f;
                hh[ob + cls] = val;
                xh0[ob + cls] = __float2half(val);
            }
        }
        #pragma unroll
        for (int g = 0; g < 4; g++) {
            int p = 48 + lq * 4 + g;
            hh[ob + p] = 0.f;
            xh0[ob + p] = __float2half(0.f);
        }
    }
}

// ---------------- setup ----------------
__global__ void zero_int_kernel(int* p, int N) {
    int i = blockIdx.x * 256 + threadIdx.x;
    if (i < N) p[i] = 0;
}
__global__ void cnt_edges_kernel(const int* __restrict__ dst, int* cnt, int E) {
    int e = blockIdx.x * 256 + threadIdx.x;
    if (e < E) atomicAdd(&cnt[dst[e]], 1);
}
__global__ void dinv_kernel(const int* __restrict__ cnt, float* dinv, int N) {
    int i = blockIdx.x * 256 + threadIdx.x;
    if (i < N) dinv[i] = rsqrtf((float)cnt[i] + 1.0f);
}
__global__ __launch_bounds__(1024) void scanA_kernel(
    const int* __restrict__ cnt, int* __restrict__ rowptr, int* __restrict__ bsum, int N)
{
    __shared__ int sd[1024];
    int t = threadIdx.x;
    int i = blockIdx.x * 1024 + t;
    sd[t] = (i < N) ? (cnt[i] + 1) : 0;        // +1: self-loop entry
    __syncthreads();
    for (int off = 1; off < 1024; off <<= 1) {
        int v = (t >= off) ? sd[t - off] : 0;
        __syncthreads();
        if (t >= off) sd[t] += v;
        __syncthreads();
    }
    if (i < N) rowptr[i + 1] = sd[t];
    if (t == 1023) bsum[blockIdx.x] = sd[1023];
}
__global__ void scanB_kernel(int* bsum, int nb) {
    __shared__ int sb[256];
    int t = threadIdx.x;
    sb[t] = (t < nb) ? bsum[t] : 0;
    __syncthreads();
    if (t == 0) { int run = 0; for (int i = 0; i < nb; i++) { int v = sb[i]; sb[i] = run; run += v; } }
    __syncthreads();
    if (t < nb) bsum[t] = sb[t];
}
__global__ __launch_bounds__(1024) void scanC_kernel(int* rowptr, const int* __restrict__ bpre, int N) {
    int i = blockIdx.x * 1024 + threadIdx.x;
    if (i < N) rowptr[i + 1] += bpre[blockIdx.x];
    if (i == 0) rowptr[0] = 0;
}
__global__ void self_fill_kernel(const int* __restrict__ rowptr, const float* __restrict__ dinv,
                                 int2* __restrict__ csre, int* __restrict__ cursor, int N) {
    int i = blockIdx.x * 256 + threadIdx.x;
    if (i < N) {
        int p = rowptr[i];
        float d = dinv[i];
        csre[p] = make_int2(i, __float_as_int(d * d));
        cursor[i] = p + 1;
    }
}
__global__ void fill_csr_kernel(const int* __restrict__ src, const int* __restrict__ dst,
    const float* __restrict__ dinv, int* cursor, int2* __restrict__ csre, int E)
{
    int e = blockIdx.x * 256 + threadIdx.x;
    if (e < E) {
        int d = dst[e], s = src[e];
        int p = atomicAdd(&cursor[d], 1);
        csre[p] = make_int2(s, __float_as_int(dinv[s] * dinv[d]));
    }
}

// ---------------- AMP iteration: wave/node, fp16 xk (one 128B line/edge) ----------------
// lane l: edge slot g = l>>3 (0..7), feature slot j = l&7 (halfs 8j..8j+7).
__global__ __launch_bounds__(256, 8) void amp5_kernel(
    const __half* __restrict__ xk, const float* __restrict__ hh,
    const int* __restrict__ rowptr, const int2* __restrict__ csre,
    __half* __restrict__ xk_new, float* __restrict__ lsm_out,
    float* __restrict__ score_out, int N, int last)
{
    const int n = (blockIdx.x * 256 + threadIdx.x) >> 6;
    if (n >= N) return;
    const int l = threadIdx.x & 63;
    const int g = l >> 3;
    const int j = l & 7;

    const int e0 = rowptr[n];
    const int e1 = rowptr[n + 1];     // >= e0+1 (self-loop)
    const int em = e1 - 1;

    float acc[8];
    #pragma unroll
    for (int i = 0; i < 8; i++) acc[i] = 0.f;

    for (int base = e0; base < e1; base += 16) {
        int ea = base + g;
        int eb = base + 8 + g;
        bool va = ea < e1;
        bool vb = eb < e1;
        int2 pa = csre[va ? ea : em];
        int2 pb = csre[vb ? eb : em];
        const uint4 qa = *(const uint4*)(xk + ((size_t)pa.x << 6) + (j << 3));
        const uint4 qb = *(const uint4*)(xk + ((size_t)pb.x << 6) + (j << 3));
        float wa = va ? __int_as_float(pa.y) : 0.f;
        float wb = vb ? __int_as_float(pb.y) : 0.f;
        const unsigned int ua[4] = {qa.x, qa.y, qa.z, qa.w};
        const unsigned int ub[4] = {qb.x, qb.y, qb.z, qb.w};
        #pragma unroll
        for (int q = 0; q < 4; q++) {
            float2 fa = __half22float2(*reinterpret_cast<const __half2*>(&ua[q]));
            float2 fb = __half22float2(*reinterpret_cast<const __half2*>(&ub[q]));
            acc[2*q]   += wa * fa.x + wb * fb.x;
            acc[2*q+1] += wa * fa.y + wb * fb.y;
        }
    }
    // reduce across 8 edge slots (lane bits 3,4,5)
    #pragma unroll
    for (int off = 8; off <= 32; off <<= 1) {
        #pragma unroll
        for (int i = 0; i < 8; i++) acc[i] += __shfl_xor(acc[i], off);
    }

    const float* hrow = hh + ((size_t)n << 6) + (j << 3);
    float4 h0 = *(const float4*)hrow;
    float4 h1 = *(const float4*)(hrow + 4);
    float hv[8] = {h0.x, h0.y, h0.z, h0.w, h1.x, h1.y, h1.z, h1.w};
    float diff[8], d2 = 0.f;
    #pragma unroll
    for (int i = 0; i < 8; i++) { diff[i] = acc[i] - hv[i]; d2 += diff[i] * diff[i]; }
    // reduce across 8 feature slots (lane bits 0,1,2)
    d2 += __shfl_xor(d2, 1); d2 += __shfl_xor(d2, 2); d2 += __shfl_xor(d2, 4);

    float rn = sqrtf(d2);
    float sc = (rn > LAMW) ? (rn - LAMW) / rn : 0.f;
    float xn[8];
    #pragma unroll
    for (int i = 0; i < 8; i++) xn[i] = hv[i] + sc * diff[i];   // pads stay exactly 0

    if (!last) {
        if (g == 0) {
            uint4 qo;
            __half2 p0 = __floats2half2_rn(xn[0], xn[1]);
            __half2 p1 = __floats2half2_rn(xn[2], xn[3]);
            __half2 p2 = __floats2half2_rn(xn[4], xn[5]);
            __half2 p3 = __floats2half2_rn(xn[6], xn[7]);
            qo.x = *reinterpret_cast<unsigned int*>(&p0);
            qo.y = *reinterpret_cast<unsigned int*>(&p1);
            qo.z = *reinterpret_cast<unsigned int*>(&p2);
            qo.w = *reinterpret_cast<unsigned int*>(&p3);
            *(uint4*)(xk_new + ((size_t)n << 6) + (j << 3)) = qo;
        }
    } else {
        if (l == 0) score_out[n] = sc;
        bool real = (j < 5);                       // j=0..4 hold the 40 real features
        float m = -3.4e38f;
        if (real) {
            #pragma unroll
            for (int i = 0; i < 8; i++) m = fmaxf(m, xn[i]);
        }
        m = fmaxf(m, __shfl_xor(m, 1));
        m = fmaxf(m, __shfl_xor(m, 2));
        m = fmaxf(m, __shfl_xor(m, 4));
        float es = 0.f;
        if (real) {
            #pragma unroll
            for (int i = 0; i < 8; i++) es += expf(xn[i] - m);
        }
        es += __shfl_xor(es, 1); es += __shfl_xor(es, 2); es += __shfl_xor(es, 4);
        float lse = m + logf(es);
        if (g == 0 && real) {
            float4 o0, o1;
            o0.x = xn[0] - lse; o0.y = xn[1] - lse; o0.z = xn[2] - lse; o0.w = xn[3] - lse;
            o1.x = xn[4] - lse; o1.y = xn[5] - lse; o1.z = xn[6] - lse; o1.w = xn[7] - lse;
            *(float4*)(lsm_out + (size_t)n * NC + (j << 3)) = o0;
            *(float4*)(lsm_out + (size_t)n * NC + (j << 3) + 4) = o1;
        }
    }
}

extern "C" void kernel_launch(void* const* d_in, const int* in_sizes, int n_in,
                              void* d_out, int out_size, void* d_ws, size_t ws_size,
                              hipStream_t stream)
{
    const float* x  = (const float*)d_in[0];
    const float* W1 = (const float*)d_in[1];
    const float* b1 = (const float*)d_in[2];
    const float* W2 = (const float*)d_in[3];
    const float* b2 = (const float*)d_in[4];
    const int* esrc = (const int*)d_in[5];
    const int* edst = (const int*)d_in[6];
    const int N = in_sizes[0] / NF;
    const int E = in_sizes[5];

    char* W = (char*)d_ws;
    size_t o = 0;
    float* hh    = (float*)(W + o);  o += (size_t)N * 64 * 4;   // f32 anchor, padded
    __half* xhX  = (__half*)(W + o); o += (size_t)N * 64 * 2;   // init / pong
    __half* xhA  = (__half*)(W + o); o += (size_t)N * 64 * 2;   // ping
    float* dinv  = (float*)(W + o);  o += (size_t)N * 4;
    int* rowptr  = (int*)(W + o);    o += (size_t)(N + 1) * 4;
    int* cnt     = (int*)(W + o);    o += (size_t)N * 4;
    int* bsum    = (int*)(W + o);    o += 256 * 4;
    o = (o + 15) & ~(size_t)15;
    int2* csre   = (int2*)(W + o);   o += (size_t)(E + N) * 8;  // edges + self-loops
    o = (o + 15) & ~(size_t)15;
    unsigned short* W1tH = (unsigned short*)(W + o); o += (size_t)NH * KPAD * 2;
    unsigned short* W1tL = (unsigned short*)(W + o); o += (size_t)NH * KPAD * 2;
    unsigned short* W2tH = (unsigned short*)(W + o); o += (size_t)48 * NH * 2;
    unsigned short* W2tL = (unsigned short*)(W + o); o += (size_t)48 * NH * 2;

    float* lsm = (float*)d_out;
    float* sco = lsm + (size_t)N * NC;

    const int gb = (N + 255) / 256;
    const int ge = (E + 255) / 256;
    const int nb = (N + 1023) / 1024;

    w1prep_kernel<<<KPAD, NH, 0, stream>>>(W1, W1tH, W1tL);
    w2prep_kernel<<<48, NH, 0, stream>>>(W2, W2tH, W2tL);
    mlp_mfma_kernel<<<(N + 63) / 64, 256, 0, stream>>>(x, b1, W1tH, W1tL, W2tH, W2tL, b2, hh, xhX, N);

    zero_int_kernel<<<gb, 256, 0, stream>>>(cnt, N);
    cnt_edges_kernel<<<ge, 256, 0, stream>>>(edst, cnt, E);
    dinv_kernel<<<gb, 256, 0, stream>>>(cnt, dinv, N);
    scanA_kernel<<<nb, 1024, 0, stream>>>(cnt, rowptr, bsum, N);
    scanB_kernel<<<1, 256, 0, stream>>>(bsum, nb);
    scanC_kernel<<<nb, 1024, 0, stream>>>(rowptr, bsum, N);
    self_fill_kernel<<<gb, 256, 0, stream>>>(rowptr, dinv, csre, cnt, N);   // cnt reused as cursor
    fill_csr_kernel<<<ge, 256, 0, stream>>>(esrc, edst, dinv, cnt, csre, E);

    const __half* xold = xhX;
    __half* bufs[2] = {xhA, xhX};    // k even -> write A, k odd -> write X
    for (int k = 0; k < KIT; k++) {
        int last = (k == KIT - 1);
        __half* xnew = bufs[k & 1];
        amp5_kernel<<<(N + 3) / 4, 256, 0, stream>>>(
            xold, hh, rowptr, csre, xnew, lsm, sco, N, last);
        xold = xnew;
    }
}